// Round 1
// baseline (2213.241 us; speedup 1.0000x reference)
//
#include <hip/hip_runtime.h>
#include <math.h>

namespace {

constexpr int kL  = 1024;
constexpr int kD  = 1024;
constexpr int kB  = 4;
constexpr int kH  = 16;
constexpr int kDK = 64;
constexpr int kHID = 4096;

__device__ __forceinline__ float wred_sum(float v) {
    #pragma unroll
    for (int o = 32; o > 0; o >>= 1) v += __shfl_xor(v, o, 64);
    return v;
}
__device__ __forceinline__ float wred_max(float v) {
    #pragma unroll
    for (int o = 32; o > 0; o >>= 1) v = fmaxf(v, __shfl_xor(v, o, 64));
    return v;
}

// out = z * (g * LN(x) + b), one block (256 thr) per row of 1024
__global__ __launch_bounds__(256) void sln_kernel(
    const float* __restrict__ x, const float* __restrict__ z,
    const float* __restrict__ lnw, const float* __restrict__ lnb,
    const float* __restrict__ g, const float* __restrict__ bt,
    float* __restrict__ out)
{
    const int row = blockIdx.x;
    const int tid = threadIdx.x;
    const size_t base = (size_t)row * kD;
    float4 xv = ((const float4*)(x + base))[tid];
    float s  = xv.x + xv.y + xv.z + xv.w;
    float sq = xv.x * xv.x + xv.y * xv.y + xv.z * xv.z + xv.w * xv.w;
    __shared__ float r1[4], r2[4];
    float ws = wred_sum(s), wq = wred_sum(sq);
    int lane = tid & 63, wid = tid >> 6;
    if (lane == 0) { r1[wid] = ws; r2[wid] = wq; }
    __syncthreads();
    float st = r1[0] + r1[1] + r1[2] + r1[3];
    float qt = r2[0] + r2[1] + r2[2] + r2[3];
    float mean = st * (1.0f / kD);
    float var  = qt * (1.0f / kD) - mean * mean;
    float rs = rsqrtf(var + 1e-5f);
    float gv = g[0], bv = bt[0];
    float4 zv = ((const float4*)(z + base))[tid];
    float4 wv = ((const float4*)lnw)[tid];
    float4 lb = ((const float4*)lnb)[tid];
    float4 o;
    o.x = zv.x * (gv * ((xv.x - mean) * rs * wv.x + lb.x) + bv);
    o.y = zv.y * (gv * ((xv.y - mean) * rs * wv.y + lb.y) + bv);
    o.z = zv.z * (gv * ((xv.z - mean) * rs * wv.z + lb.z) + bv);
    o.w = zv.w * (gv * ((xv.w - mean) * rs * wv.w + lb.w) + bv);
    ((float4*)(out + base))[tid] = o;
}

// Generic tiled GEMM: C = scale*A@B (+bias) (gelu) (+res)
// 64x64 tile, BK=16, 256 threads, 4x4 micro-tile.
// mode 0: plain (blockIdx.z==0). mode 1: scores (z = p = h*B+b):
//   A=qh (offset b*L*D + h*64), B=khT (offset p*64*L), C=attn (offset p*L*L)
// mode 2: PV: A=attn (p*L*L), B=vh (b*L*D + h*64), C=ctx (b*L*D + h*64)
__global__ __launch_bounds__(256) void gemm_kernel(
    const float* __restrict__ A, int lda,
    const float* __restrict__ Bm, int ldb,
    float* __restrict__ C, int ldc,
    int K,
    const float* __restrict__ bias,
    const float* __restrict__ res,
    float scale, int gelu, int mode)
{
    __shared__ __align__(16) float As[16][64];   // [k][m]
    __shared__ __align__(16) float Bs[16][64];   // [k][n]
    if (mode == 1) {
        int p = blockIdx.z, b = p & 3, h = p >> 2;
        A  += (size_t)b * (kL * kD) + h * kDK;
        Bm += (size_t)p * (kDK * kL);
        C  += (size_t)p * (kL * kL);
    } else if (mode == 2) {
        int p = blockIdx.z, b = p & 3, h = p >> 2;
        A  += (size_t)p * (kL * kL);
        Bm += (size_t)b * (kL * kD) + h * kDK;
        C  += (size_t)b * (kL * kD) + h * kDK;
    }
    const int tid = threadIdx.x;
    const int tx = tid & 15, ty = tid >> 4;
    const int m0 = blockIdx.y * 64, n0 = blockIdx.x * 64;
    const int am = tid >> 2, ak = (tid & 3) * 4;   // A load: float4 along k
    float acc[4][4] = {};
    for (int k0 = 0; k0 < K; k0 += 16) {
        float4 av = *(const float4*)(A + (size_t)(m0 + am) * lda + (k0 + ak));
        As[ak + 0][am] = av.x;
        As[ak + 1][am] = av.y;
        As[ak + 2][am] = av.z;
        As[ak + 3][am] = av.w;
        #pragma unroll
        for (int i = 0; i < 4; i++) {
            int li = tid + i * 256;
            int kk = li >> 6, n = li & 63;
            Bs[kk][n] = Bm[(size_t)(k0 + kk) * ldb + (n0 + n)];
        }
        __syncthreads();
        #pragma unroll
        for (int kk = 0; kk < 16; kk++) {
            float a[4], b[4];
            *(float4*)a = *(const float4*)&As[kk][ty * 4];
            *(float4*)b = *(const float4*)&Bs[kk][tx * 4];
            #pragma unroll
            for (int i = 0; i < 4; i++)
                #pragma unroll
                for (int j = 0; j < 4; j++)
                    acc[i][j] = fmaf(a[i], b[j], acc[i][j]);
        }
        __syncthreads();
    }
    #pragma unroll
    for (int i = 0; i < 4; i++) {
        int m = m0 + ty * 4 + i;
        #pragma unroll
        for (int j = 0; j < 4; j++) {
            int n = n0 + tx * 4 + j;
            float v = acc[i][j] * scale;
            if (bias) v += bias[n];
            if (gelu) v = 0.5f * v * (1.0f + erff(v * 0.70710678118654752440f));
            if (res) v += res[(size_t)m * ldc + n];
            C[(size_t)m * ldc + n] = v;
        }
    }
}

// khT[p=h*B+b][d][j] = kh[b*L + j][h*64 + d]; 32x32 LDS-tiled transpose
__global__ __launch_bounds__(256) void transpose_kh(
    const float* __restrict__ kh, float* __restrict__ khT)
{
    __shared__ float t[32][33];
    int p = blockIdx.z, b = p & 3, h = p >> 2;
    int j0 = blockIdx.x * 32, d0 = blockIdx.y * 32;
    int tx = threadIdx.x & 31, tyy = threadIdx.x >> 5;   // 32 x 8
    const float* src = kh + (size_t)b * (kL * kD) + h * kDK;
    #pragma unroll
    for (int i = 0; i < 4; i++) {
        int r = tyy + i * 8;
        t[r][tx] = src[(size_t)(j0 + r) * kD + d0 + tx];
    }
    __syncthreads();
    float* dst = khT + (size_t)p * (kDK * kL);
    #pragma unroll
    for (int i = 0; i < 4; i++) {
        int d = tyy + i * 8;
        dst[(size_t)(d0 + d) * kL + j0 + tx] = t[tx][d];
    }
}

// in-place row softmax over 1024 cols; one block per row
__global__ __launch_bounds__(256) void softmax_kernel(float* __restrict__ attn)
{
    const size_t row = blockIdx.x;
    const int tid = threadIdx.x;
    float4* p = (float4*)(attn + row * kL);
    float4 x = p[tid];
    float mx = fmaxf(fmaxf(x.x, x.y), fmaxf(x.z, x.w));
    mx = wred_max(mx);
    __shared__ float rm[4], rs[4];
    int lane = tid & 63, wid = tid >> 6;
    if (lane == 0) rm[wid] = mx;
    __syncthreads();
    float bm = fmaxf(fmaxf(rm[0], rm[1]), fmaxf(rm[2], rm[3]));
    float4 e;
    e.x = __expf(x.x - bm); e.y = __expf(x.y - bm);
    e.z = __expf(x.z - bm); e.w = __expf(x.w - bm);
    float s = e.x + e.y + e.z + e.w;
    s = wred_sum(s);
    if (lane == 0) rs[wid] = s;
    __syncthreads();
    float inv = 1.0f / (rs[0] + rs[1] + rs[2] + rs[3]);
    e.x *= inv; e.y *= inv; e.z *= inv; e.w *= inv;
    p[tid] = e;
}

} // namespace

extern "C" void kernel_launch(void* const* d_in, const int* in_sizes, int n_in,
                              void* d_out, int out_size, void* d_ws, size_t ws_size,
                              hipStream_t stream)
{
    (void)in_sizes; (void)n_in; (void)out_size; (void)ws_size;
    const float* q      = (const float*)d_in[0];
    const float* k      = (const float*)d_in[1];
    const float* v      = (const float*)d_in[2];
    const float* z      = (const float*)d_in[3];
    const float* wq_w   = (const float*)d_in[4];
    const float* wq_b   = (const float*)d_in[5];
    const float* wk_w   = (const float*)d_in[6];
    const float* wk_b   = (const float*)d_in[7];
    const float* wv_w   = (const float*)d_in[8];
    const float* wv_b   = (const float*)d_in[9];
    const float* fc_w   = (const float*)d_in[10];
    const float* fc_b   = (const float*)d_in[11];
    const float* mlp1_w = (const float*)d_in[12];
    const float* mlp1_b = (const float*)d_in[13];
    const float* mlp2_w = (const float*)d_in[14];
    const float* mlp2_b = (const float*)d_in[15];
    const float* ln1_w  = (const float*)d_in[16];
    const float* ln1_b  = (const float*)d_in[17];
    const float* g1     = (const float*)d_in[18];
    const float* b1     = (const float*)d_in[19];
    const float* ln2_w  = (const float*)d_in[20];
    const float* ln2_b  = (const float*)d_in[21];
    const float* g2     = (const float*)d_in[22];
    const float* b2     = (const float*)d_in[23];

    float* out0 = (float*)d_out;                          // (B,L,D) = 4M floats
    float* attn = (float*)d_out + (size_t)kB * kL * kD;   // (H*B,L,L) = 64M floats

    float* ws = (float*)d_ws;
    const size_t M4 = (size_t)4 * 1024 * 1024;
    float* qp  = ws;            // residual 1 (post-SLN q)
    float* qh  = ws + 1 * M4;
    float* kh  = ws + 2 * M4;
    float* vh  = ws + 3 * M4;
    float* khT = ws + 4 * M4;   // 4M..5M (x4M floats): [p][d][j]
    float* ctx  = kh;           // kh dead after transpose
    float* out1 = qh;           // qh dead after scores
    float* h2   = qp;           // qp dead after fc residual
    float* hid  = vh;           // 3*M4..7*M4 (16M floats); vh,khT dead by then

    dim3 blk(256);
    // 1) q' = SLN(q, z)
    sln_kernel<<<dim3(kB * kL), blk, 0, stream>>>(q, z, ln1_w, ln1_b, g1, b1, qp);
    // 2-4) QKV projections
    gemm_kernel<<<dim3(16, 64, 1), blk, 0, stream>>>(qp, kD, wq_w, kH * kDK, qh, kH * kDK, kD, wq_b, nullptr, 1.0f, 0, 0);
    gemm_kernel<<<dim3(16, 64, 1), blk, 0, stream>>>(k,  kD, wk_w, kH * kDK, kh, kH * kDK, kD, wk_b, nullptr, 1.0f, 0, 0);
    gemm_kernel<<<dim3(16, 64, 1), blk, 0, stream>>>(v,  kD, wv_w, kH * kDK, vh, kH * kDK, kD, wv_b, nullptr, 1.0f, 0, 0);
    // 5) K^T per (h,b)
    transpose_kh<<<dim3(32, 2, 64), blk, 0, stream>>>(kh, khT);
    // 6) raw scores straight into attn output region, scale=1/sqrt(64)
    gemm_kernel<<<dim3(16, 16, 64), blk, 0, stream>>>(qh, kD, khT, kL, attn, kL, kDK, nullptr, nullptr, 0.125f, 0, 1);
    // 7) softmax in place
    softmax_kernel<<<dim3(64 * kL), blk, 0, stream>>>(attn);
    // 8) ctx = P @ V
    gemm_kernel<<<dim3(1, 16, 64), blk, 0, stream>>>(attn, kL, vh, kD, ctx, kD, kL, nullptr, nullptr, 1.0f, 0, 2);
    // 9) out1 = ctx @ fc_w + fc_b + q'
    gemm_kernel<<<dim3(16, 64, 1), blk, 0, stream>>>(ctx, kD, fc_w, kD, out1, kD, kD, fc_b, qp, 1.0f, 0, 0);
    // 10) h2 = SLN(out1, z)
    sln_kernel<<<dim3(kB * kL), blk, 0, stream>>>(out1, z, ln2_w, ln2_b, g2, b2, h2);
    // 11) hid = gelu(h2 @ mlp1_w + mlp1_b)
    gemm_kernel<<<dim3(64, 64, 1), blk, 0, stream>>>(h2, kD, mlp1_w, kHID, hid, kHID, kD, mlp1_b, nullptr, 1.0f, 1, 0);
    // 12) out0 = hid @ mlp2_w + mlp2_b + out1
    gemm_kernel<<<dim3(16, 64, 1), blk, 0, stream>>>(hid, kHID, mlp2_w, kD, out0, kD, kHID, mlp2_b, out1, 1.0f, 0, 0);
}

// Round 2
// 1025.078 us; speedup vs baseline: 2.1591x; 2.1591x over previous
//
#include <hip/hip_runtime.h>
#include <math.h>

namespace {

constexpr int kL  = 1024;
constexpr int kD  = 1024;
constexpr int kB  = 4;
constexpr int kH  = 16;
constexpr int kDK = 64;
constexpr int kHID = 4096;

typedef unsigned short ushort_t;
typedef short  s16x8 __attribute__((ext_vector_type(8)));   // 8 bf16 (4 VGPRs) MFMA frag
typedef float  f32x4 __attribute__((ext_vector_type(4)));
typedef unsigned short u16x4 __attribute__((ext_vector_type(4)));

// fp32 -> bf16 round-to-nearest-even
__device__ __forceinline__ ushort_t f2bf(float f) {
    unsigned u = __float_as_uint(f);
    unsigned r = u + 0x7fffu + ((u >> 16) & 1u);
    return (ushort_t)(r >> 16);
}

// async global->LDS, 16B per lane. LDS dest = wave-uniform base + lane*16.
__device__ __forceinline__ void gld16(const void* g, void* l) {
    __builtin_amdgcn_global_load_lds((__attribute__((address_space(1))) void*)(g),
                                     (__attribute__((address_space(3))) void*)(l),
                                     16, 0, 0);
}

__device__ __forceinline__ float wred_sum(float v) {
    #pragma unroll
    for (int o = 32; o > 0; o >>= 1) v += __shfl_xor(v, o, 64);
    return v;
}
__device__ __forceinline__ float wred_max(float v) {
    #pragma unroll
    for (int o = 32; o > 0; o >>= 1) v = fmaxf(v, __shfl_xor(v, o, 64));
    return v;
}

// out = z * (g * LN(x) + b). Writes bf16 always, fp32 optionally.
__global__ __launch_bounds__(256) void sln_kernel(
    const float* __restrict__ x, const float* __restrict__ z,
    const float* __restrict__ lnw, const float* __restrict__ lnb,
    const float* __restrict__ g, const float* __restrict__ bt,
    float* __restrict__ outf, ushort_t* __restrict__ outb)
{
    const int row = blockIdx.x;
    const int tid = threadIdx.x;
    const size_t base = (size_t)row * kD;
    float4 xv = ((const float4*)(x + base))[tid];
    float s  = xv.x + xv.y + xv.z + xv.w;
    float sq = xv.x * xv.x + xv.y * xv.y + xv.z * xv.z + xv.w * xv.w;
    __shared__ float r1[4], r2[4];
    float ws = wred_sum(s), wq = wred_sum(sq);
    int lane = tid & 63, wid = tid >> 6;
    if (lane == 0) { r1[wid] = ws; r2[wid] = wq; }
    __syncthreads();
    float st = r1[0] + r1[1] + r1[2] + r1[3];
    float qt = r2[0] + r2[1] + r2[2] + r2[3];
    float mean = st * (1.0f / kD);
    float var  = qt * (1.0f / kD) - mean * mean;
    float rs = rsqrtf(var + 1e-5f);
    float gv = g[0], bv = bt[0];
    float4 zv = ((const float4*)(z + base))[tid];
    float4 wv = ((const float4*)lnw)[tid];
    float4 lb = ((const float4*)lnb)[tid];
    float4 o;
    o.x = zv.x * (gv * ((xv.x - mean) * rs * wv.x + lb.x) + bv);
    o.y = zv.y * (gv * ((xv.y - mean) * rs * wv.y + lb.y) + bv);
    o.z = zv.z * (gv * ((xv.z - mean) * rs * wv.z + lb.z) + bv);
    o.w = zv.w * (gv * ((xv.w - mean) * rs * wv.w + lb.w) + bv);
    if (outf) ((float4*)(outf + base))[tid] = o;
    u16x4 ob; ob[0] = f2bf(o.x); ob[1] = f2bf(o.y); ob[2] = f2bf(o.z); ob[3] = f2bf(o.w);
    ((u16x4*)(outb + base))[tid] = ob;
}

// elementwise fp32 -> bf16, one float4 per thread
__global__ __launch_bounds__(256) void cvt_bf16(
    const float* __restrict__ x, ushort_t* __restrict__ y)
{
    int i = blockIdx.x * 256 + threadIdx.x;
    f32x4 v = ((const f32x4*)x)[i];
    u16x4 o; o[0] = f2bf(v[0]); o[1] = f2bf(v[1]); o[2] = f2bf(v[2]); o[3] = f2bf(v[3]);
    ((u16x4*)y)[i] = o;
}

// transpose + convert: src fp32 [R][C] -> dst bf16 [C][R]
__global__ __launch_bounds__(256) void twcvt(
    const float* __restrict__ src, ushort_t* __restrict__ dst, int R, int C)
{
    __shared__ float t[32][33];
    int c0 = blockIdx.x * 32, r0 = blockIdx.y * 32;
    int tx = threadIdx.x & 31, ty = threadIdx.x >> 5;
    #pragma unroll
    for (int i = 0; i < 4; i++) {
        int r = ty + i * 8;
        t[r][tx] = src[(size_t)(r0 + r) * C + c0 + tx];
    }
    __syncthreads();
    #pragma unroll
    for (int i = 0; i < 4; i++) {
        int c = ty + i * 8;
        dst[(size_t)(c0 + c) * R + r0 + tx] = f2bf(t[tx][c]);
    }
}

// vh bf16 [b][j][h*64+d] -> vhT bf16 [p=h*4+b][d][j]
__global__ __launch_bounds__(256) void vtrans(
    const ushort_t* __restrict__ vh, ushort_t* __restrict__ vhT)
{
    __shared__ ushort_t t[32][33];
    int p = blockIdx.z, b = p & 3, h = p >> 2;
    int j0 = blockIdx.x * 32, d0 = blockIdx.y * 32;
    int tx = threadIdx.x & 31, ty = threadIdx.x >> 5;
    const ushort_t* src = vh + (size_t)b * (kL * kD) + h * kDK;
    #pragma unroll
    for (int i = 0; i < 4; i++) {
        int j = ty + i * 8;
        t[j][tx] = src[(size_t)(j0 + j) * kD + d0 + tx];
    }
    __syncthreads();
    ushort_t* dst = vhT + (size_t)p * (kDK * kL);
    #pragma unroll
    for (int i = 0; i < 4; i++) {
        int d = ty + i * 8;
        dst[(size_t)(d0 + d) * kL + j0 + tx] = t[tx][d];
    }
}

// MFMA GEMM: C = scale*(A @ Bt^T) (+bias)(gelu)(+res). A[M][K], Bt[N][K] bf16.
// 128x128 tile, BK=32, 256 thr (4 waves, each 64x64). m97 structure.
// flags: 1 = gelu, 2 = bf16 output. mode 1 = attention scores batch (z = p).
__global__ __launch_bounds__(256) void mgemm(
    const ushort_t* __restrict__ A, int lda,
    const ushort_t* __restrict__ Bt, int ldb,
    void* __restrict__ Cv, int ldc, int K,
    const float* __restrict__ bias, const float* __restrict__ res,
    float scale, int flags, int mode)
{
    __shared__ __align__(16) ushort_t As[128 * 32];
    __shared__ __align__(16) ushort_t Bs[128 * 32];
    float*    Cf = (float*)Cv;
    ushort_t* Cb = (ushort_t*)Cv;
    if (mode == 1) {
        int p = blockIdx.z;
        size_t off = (size_t)(p & 3) * (kL * kD) + (size_t)(p >> 2) * kDK;
        A += off; Bt += off;
        Cf += (size_t)p * kL * kL;
    }
    const int tid = threadIdx.x;
    const int lane = tid & 63, w = tid >> 6;
    const int m0 = blockIdx.y * 128, n0 = blockIdx.x * 128;
    // staging: chunk = 16B (8 bf16). chunk p: row r=p>>2, stored col = c ^ (r&3)
    const int r0 = tid >> 2;
    const int c0 = (tid & 3) ^ (r0 & 3);
    const ushort_t* Ag0 = A  + (size_t)(m0 + r0) * lda + c0 * 8;
    const ushort_t* Ag1 = Ag0 + (size_t)64 * lda;
    const ushort_t* Bg0 = Bt + (size_t)(n0 + r0) * ldb + c0 * 8;
    const ushort_t* Bg1 = Bg0 + (size_t)64 * ldb;
    char* AsW = (char*)As + w * 1024;   // wave-uniform LDS dest
    char* BsW = (char*)Bs + w * 1024;
    const int wm = (w & 1) * 64, wn = (w >> 1) * 64;
    const int fn = lane & 15, q = lane >> 4;
    int aoff[4], boff[4];
    #pragma unroll
    for (int i = 0; i < 4; i++) {
        int ra = wm + i * 16 + fn;
        aoff[i] = (ra * 4 + (q ^ (ra & 3))) * 16;
        int rb = wn + i * 16 + fn;
        boff[i] = (rb * 4 + (q ^ (rb & 3))) * 16;
    }
    f32x4 acc[4][4] = {};
    for (int k0 = 0; k0 < K; k0 += 32) {
        gld16(Ag0 + k0, AsW);
        gld16(Ag1 + k0, AsW + 4096);
        gld16(Bg0 + k0, BsW);
        gld16(Bg1 + k0, BsW + 4096);
        __syncthreads();
        s16x8 af[4], bfr[4];
        #pragma unroll
        for (int i = 0; i < 4; i++) {
            af[i]  = *(const s16x8*)((const char*)As + aoff[i]);
            bfr[i] = *(const s16x8*)((const char*)Bs + boff[i]);
        }
        #pragma unroll
        for (int mi = 0; mi < 4; mi++)
            #pragma unroll
            for (int ni = 0; ni < 4; ni++)
                acc[mi][ni] = __builtin_amdgcn_mfma_f32_16x16x32_bf16(
                    af[mi], bfr[ni], acc[mi][ni], 0, 0, 0);
        __syncthreads();
    }
    #pragma unroll
    for (int mi = 0; mi < 4; mi++) {
        #pragma unroll
        for (int ni = 0; ni < 4; ni++) {
            #pragma unroll
            for (int r = 0; r < 4; r++) {
                int gm = m0 + wm + mi * 16 + q * 4 + r;   // C/D row = quad*4+reg
                int gn = n0 + wn + ni * 16 + fn;          // C/D col = lane&15
                float v = acc[mi][ni][r] * scale;
                if (bias) v += bias[gn];
                if (flags & 1) v = 0.5f * v * (1.0f + erff(v * 0.70710678118654752f));
                if (res) v += res[(size_t)gm * ldc + gn];
                if (flags & 2) Cb[(size_t)gm * ldc + gn] = f2bf(v);
                else           Cf[(size_t)gm * ldc + gn] = v;
            }
        }
    }
}

// PV: ctx[b][i][h*64+d] = sum_j P[p][i][j] * V[p][d][j]^T. N=64 per head.
// 128x64 tile: 4 waves as 2x2, wave tile 64x32. A (probs) staged fp32->bf16
// through registers; B (vhT) via global_load_lds.
__global__ __launch_bounds__(256) void pv_gemm(
    const float* __restrict__ P, const ushort_t* __restrict__ vhT,
    ushort_t* __restrict__ ctx)
{
    __shared__ __align__(16) ushort_t As[128 * 40];   // row stride 40 bf16 = 80B
    __shared__ __align__(16) ushort_t Bs[64 * 32];
    const int p = blockIdx.z, b = p & 3, h = p >> 2;
    const int m0 = blockIdx.y * 128;
    const float*    Pb = P   + (size_t)p * kL * kL;
    const ushort_t* Vb = vhT + (size_t)p * (kDK * kL);
    const int tid = threadIdx.x, lane = tid & 63, w = tid >> 6;
    const int wm = (w & 1) * 64, wn = (w >> 1) * 32;
    const int fn = lane & 15, q = lane >> 4;
    const int br = tid >> 2;
    const int bc = (tid & 3) ^ (br & 3);
    const ushort_t* Bg = Vb + (size_t)br * kL + bc * 8;
    char* BsW = (char*)Bs + w * 1024;
    int aoff[4], boff[2];
    #pragma unroll
    for (int i = 0; i < 4; i++) { int ra = wm + i * 16 + fn; aoff[i] = ra * 80 + q * 16; }
    #pragma unroll
    for (int i = 0; i < 2; i++) {
        int rb = wn + i * 16 + fn;
        boff[i] = (rb * 4 + (q ^ (rb & 3))) * 16;
    }
    f32x4 acc[4][2] = {};
    for (int k0 = 0; k0 < kL; k0 += 32) {
        gld16(Bg + k0, BsW);
        #pragma unroll
        for (int i = 0; i < 4; i++) {
            int idx = tid + 256 * i;
            int r = idx >> 3, c4 = idx & 7;
            f32x4 vv = *(const f32x4*)(Pb + (size_t)(m0 + r) * kL + k0 + c4 * 4);
            u16x4 o; o[0] = f2bf(vv[0]); o[1] = f2bf(vv[1]); o[2] = f2bf(vv[2]); o[3] = f2bf(vv[3]);
            *(u16x4*)((char*)As + r * 80 + c4 * 8) = o;
        }
        __syncthreads();
        s16x8 af[4], bfr[2];
        #pragma unroll
        for (int i = 0; i < 4; i++) af[i]  = *(const s16x8*)((const char*)As + aoff[i]);
        #pragma unroll
        for (int i = 0; i < 2; i++) bfr[i] = *(const s16x8*)((const char*)Bs + boff[i]);
        #pragma unroll
        for (int mi = 0; mi < 4; mi++)
            #pragma unroll
            for (int ni = 0; ni < 2; ni++)
                acc[mi][ni] = __builtin_amdgcn_mfma_f32_16x16x32_bf16(
                    af[mi], bfr[ni], acc[mi][ni], 0, 0, 0);
        __syncthreads();
    }
    #pragma unroll
    for (int mi = 0; mi < 4; mi++) {
        #pragma unroll
        for (int ni = 0; ni < 2; ni++) {
            #pragma unroll
            for (int r = 0; r < 4; r++) {
                int gm = m0 + wm + mi * 16 + q * 4 + r;
                int gd = wn + ni * 16 + fn;
                ctx[(size_t)b * (kL * kD) + (size_t)gm * kD + h * 64 + gd] =
                    f2bf(acc[mi][ni][r]);
            }
        }
    }
}

// in-place row softmax over 1024 cols
__global__ __launch_bounds__(256) void softmax_kernel(float* __restrict__ attn)
{
    const size_t row = blockIdx.x;
    const int tid = threadIdx.x;
    float4* p = (float4*)(attn + row * kL);
    float4 x = p[tid];
    float mx = fmaxf(fmaxf(x.x, x.y), fmaxf(x.z, x.w));
    mx = wred_max(mx);
    __shared__ float rm[4], rs[4];
    int lane = tid & 63, wid = tid >> 6;
    if (lane == 0) rm[wid] = mx;
    __syncthreads();
    float bm = fmaxf(fmaxf(rm[0], rm[1]), fmaxf(rm[2], rm[3]));
    float4 e;
    e.x = __expf(x.x - bm); e.y = __expf(x.y - bm);
    e.z = __expf(x.z - bm); e.w = __expf(x.w - bm);
    float s = e.x + e.y + e.z + e.w;
    s = wred_sum(s);
    if (lane == 0) rs[wid] = s;
    __syncthreads();
    float inv = 1.0f / (rs[0] + rs[1] + rs[2] + rs[3]);
    e.x *= inv; e.y *= inv; e.z *= inv; e.w *= inv;
    p[tid] = e;
}

} // namespace

extern "C" void kernel_launch(void* const* d_in, const int* in_sizes, int n_in,
                              void* d_out, int out_size, void* d_ws, size_t ws_size,
                              hipStream_t stream)
{
    (void)in_sizes; (void)n_in; (void)out_size; (void)ws_size;
    const float* q      = (const float*)d_in[0];
    const float* k      = (const float*)d_in[1];
    const float* v      = (const float*)d_in[2];
    const float* z      = (const float*)d_in[3];
    const float* wq_w   = (const float*)d_in[4];
    const float* wq_b   = (const float*)d_in[5];
    const float* wk_w   = (const float*)d_in[6];
    const float* wk_b   = (const float*)d_in[7];
    const float* wv_w   = (const float*)d_in[8];
    const float* wv_b   = (const float*)d_in[9];
    const float* fc_w   = (const float*)d_in[10];
    const float* fc_b   = (const float*)d_in[11];
    const float* mlp1_w = (const float*)d_in[12];
    const float* mlp1_b = (const float*)d_in[13];
    const float* mlp2_w = (const float*)d_in[14];
    const float* mlp2_b = (const float*)d_in[15];
    const float* ln1_w  = (const float*)d_in[16];
    const float* ln1_b  = (const float*)d_in[17];
    const float* g1     = (const float*)d_in[18];
    const float* b1     = (const float*)d_in[19];
    const float* ln2_w  = (const float*)d_in[20];
    const float* ln2_b  = (const float*)d_in[21];
    const float* g2     = (const float*)d_in[22];
    const float* b2     = (const float*)d_in[23];

    float* out0 = (float*)d_out;                          // (B,L,D)
    float* attn = (float*)d_out + (size_t)kB * kL * kD;   // (H*B,L,L)

    // workspace arena (104 MB peak, with lifetime-based overlays)
    char* arena = (char*)d_ws;
    const size_t MB = 1u << 20;
    float*    qp   = (float*)(arena);                  // [0,16M)  fp32 q' (residual)
    ushort_t* qh   = (ushort_t*)(arena + 16 * MB);     // [16,24)
    ushort_t* kh   = (ushort_t*)(arena + 24 * MB);     // [24,32)
    ushort_t* vh   = (ushort_t*)(arena + 32 * MB);     // [32,40)
    ushort_t* vhT  = (ushort_t*)(arena + 40 * MB);     // [40,48)
    ushort_t* hid  = (ushort_t*)(arena + 16 * MB);     // [16,48)  overlays qh..vhT (dead)
    ushort_t* qb   = (ushort_t*)(arena + 48 * MB);     // [48,56)
    ushort_t* kb   = (ushort_t*)(arena + 56 * MB);     // [56,64)
    float*    out1 = (float*)(arena + 48 * MB);        // [48,64)  overlays qb,kb (dead)
    ushort_t* vb   = (ushort_t*)(arena + 64 * MB);     // [64,72)
    ushort_t* ctx  = (ushort_t*)(arena + 64 * MB);     // [64,72)  overlays vb (dead)
    ushort_t* h2   = (ushort_t*)(arena + 72 * MB);     // [72,80)
    ushort_t* wqT  = (ushort_t*)(arena + 80 * MB);
    ushort_t* wkT  = (ushort_t*)(arena + 82 * MB);
    ushort_t* wvT  = (ushort_t*)(arena + 84 * MB);
    ushort_t* fcT  = (ushort_t*)(arena + 86 * MB);
    ushort_t* m1T  = (ushort_t*)(arena + 88 * MB);     // [88,96)
    ushort_t* m2T  = (ushort_t*)(arena + 96 * MB);     // [96,104)

    dim3 blk(256);
    // 0) weight transpose+convert to bf16 [out][in]
    twcvt<<<dim3(32, 32), blk, 0, stream>>>(wq_w, wqT, kD, kH * kDK);
    twcvt<<<dim3(32, 32), blk, 0, stream>>>(wk_w, wkT, kD, kH * kDK);
    twcvt<<<dim3(32, 32), blk, 0, stream>>>(wv_w, wvT, kD, kH * kDK);
    twcvt<<<dim3(32, 32), blk, 0, stream>>>(fc_w, fcT, kH * kDK, kD);
    twcvt<<<dim3(128, 32), blk, 0, stream>>>(mlp1_w, m1T, kD, kHID);
    twcvt<<<dim3(32, 128), blk, 0, stream>>>(mlp2_w, m2T, kHID, kD);
    // 0b) k, v -> bf16
    cvt_bf16<<<dim3(4096), blk, 0, stream>>>(k, kb);
    cvt_bf16<<<dim3(4096), blk, 0, stream>>>(v, vb);
    // 1) q' = SLN(q, z): fp32 (residual) + bf16 (GEMM input)
    sln_kernel<<<dim3(kB * kL), blk, 0, stream>>>(q, z, ln1_w, ln1_b, g1, b1, qp, qb);
    // 2-4) QKV projections -> bf16 heads
    mgemm<<<dim3(8, 32, 1), blk, 0, stream>>>(qb, kD, wqT, kD, qh, kD, kD, wq_b, nullptr, 1.0f, 2, 0);
    mgemm<<<dim3(8, 32, 1), blk, 0, stream>>>(kb, kD, wkT, kD, kh, kD, kD, wk_b, nullptr, 1.0f, 2, 0);
    mgemm<<<dim3(8, 32, 1), blk, 0, stream>>>(vb, kD, wvT, kD, vh, kD, kD, wv_b, nullptr, 1.0f, 2, 0);
    // 5) V^T per head
    vtrans<<<dim3(32, 2, 64), blk, 0, stream>>>(vh, vhT);
    // 6) scores = qh @ kh^T * 1/8 -> attn (fp32, d_out)
    mgemm<<<dim3(8, 8, 64), blk, 0, stream>>>(qh, kD, kh, kD, attn, kL, kDK, nullptr, nullptr, 0.125f, 0, 1);
    // 7) softmax in place
    softmax_kernel<<<dim3(64 * kL), blk, 0, stream>>>(attn);
    // 8) ctx = P @ V -> bf16
    pv_gemm<<<dim3(1, 8, 64), blk, 0, stream>>>(attn, vhT, ctx);
    // 9) out1 = ctx @ fc_w + fc_b + q'  (fp32)
    mgemm<<<dim3(8, 32, 1), blk, 0, stream>>>(ctx, kD, fcT, kD, out1, kD, kD, fc_b, qp, 1.0f, 0, 0);
    // 10) h2 = SLN(out1, z) -> bf16 only
    sln_kernel<<<dim3(kB * kL), blk, 0, stream>>>(out1, z, ln2_w, ln2_b, g2, b2, nullptr, h2);
    // 11) hid = gelu(h2 @ mlp1 + b) -> bf16
    mgemm<<<dim3(32, 32, 1), blk, 0, stream>>>(h2, kD, m1T, kD, hid, kHID, kD, mlp1_b, nullptr, 1.0f, 3, 0);
    // 12) out0 = hid @ mlp2 + b + out1 (fp32)
    mgemm<<<dim3(8, 32, 1), blk, 0, stream>>>(hid, kHID, m2T, kHID, out0, kD, kHID, mlp2_b, out1, 1.0f, 0, 0);
}